// Round 12
// baseline (118.628 us; speedup 1.0000x reference)
//
#include <hip/hip_runtime.h>
#include <stdint.h>

#define NQ 10
#define DIMQ 1024
#define BATCH 4096

typedef float f32x2 __attribute__((ext_vector_type(2)));

#if __has_builtin(__builtin_amdgcn_permlane16_swap)
#define HAS_PL16 1
#else
#define HAS_PL16 0
#endif

// Layer's 10 CNOTs composed as a GF(2)-linear index map (scatter form).
__host__ __device__ constexpr int cperm_c(int x, int r) {
  for (int q = 0; q < NQ; ++q) {
    const int c = 9 - q;
    int t = c - r; if (t < 0) t += NQ;
    x ^= ((x >> c) & 1) << t;
  }
  return x;
}
// Epilogue sign masks (layer-3 perm r=4 folded into signs).
constexpr int amask(int q) {
  int a = 0;
  for (int b = 0; b < 6; ++b) a |= ((cperm_c(1 << b, 4) >> (9 - q)) & 1) << b;
  return a;
}
constexpr int mmask(int q) {
  int m = 0;
  for (int b = 0; b < 4; ++b) m |= ((cperm_c(1 << (6 + b), 4) >> (9 - q)) & 1) << b;
  return m;
}

// ------------------------------------------------------- gate precompute ---
// Rot(phi,th,om) = RZ(om)*RY(th)*RZ(phi); per layer all RZ's merge into
// diagonals. ryc[40] = (cos th/2, sin th/2). D0 = first phi-diagonal.
// E_l = omega-diag(l) merged ACROSS the CNOT perm with phi-diag(l+1).
// Layer-3 omega diagonal dropped (|amp|^2 kills pure phase).
__global__ __launch_bounds__(64) void prep_g(const float* __restrict__ wts,
                                             float* __restrict__ Gg) {
  const int t = threadIdx.x;
  if (t < 40) {
    float th = wts[t * 3 + 1];
    ((float2*)Gg)[t] = make_float2(cosf(0.5f * th), sinf(0.5f * th));
  }
  f32x2* D0 = (f32x2*)(Gg + 128);
  f32x2* E  = D0 + 1024;           // E0, E1, E2 consecutive (1024 each)
  auto sphase = [&](int l, int i, int comp) {   // comp: 0=phi, 2=omega
    float s = 0.f;
    for (int q = 0; q < 10; ++q) {
      float sg = ((i >> (9 - q)) & 1) ? 0.5f : -0.5f;
      s += sg * wts[(l * 10 + q) * 3 + comp];
    }
    return s;
  };
  for (int k = 0; k < 16; ++k) {
    int idx = (k << 6) | t;
    float p0 = sphase(0, idx, 0);
    D0[idx] = (f32x2){cosf(p0), sinf(p0)};
    #pragma unroll 1
    for (int l = 0; l < 3; ++l) {
      float a = sphase(l, idx, 2) + sphase(l + 1, cperm_c(idx, l + 1), 0);
      E[l * 1024 + idx] = (f32x2){cosf(a), sinf(a)};
    }
  }
}

// ---- VALU-pipe lane shuffles ----
template<int CTRL>
__device__ __forceinline__ float dpp1(float x) {
  return __int_as_float(
      __builtin_amdgcn_update_dpp(0, __float_as_int(x), CTRL, 0xF, 0xF, true));
}
// quad_perm xor1=0xB1, xor2=0x4E, xor3=0x1B; row_half_mirror(^7)=0x141;
// row_ror:8 = 0x128 == xor8 within a 16-lane row (R12: 1 DPP, was 2).
template<int P>   // P = lane bit, 0..3 (DPP only)
__device__ __forceinline__ float shufl(float x) {
  if constexpr (P == 0)      return dpp1<0xB1>(x);
  else if constexpr (P == 1) return dpp1<0x4E>(x);
  else if constexpr (P == 2) return dpp1<0x141>(dpp1<0x1B>(x));
  else                       return dpp1<0x128>(x);   // row_ror:8 == ^8
}
__device__ __forceinline__ float x16(float x, bool hi) {
#if HAS_PL16
  auto rr = __builtin_amdgcn_permlane16_swap(__float_as_uint(x),
                                             __float_as_uint(x), false, false);
  return __uint_as_float(hi ? rr[0] : rr[1]);
#else
  (void)hi;
  return __int_as_float(__builtin_amdgcn_ds_swizzle(__float_as_int(x), 0x401F));
#endif
}

// Wave sum -> uniform scalar.
__device__ __forceinline__ float red64(float v) {
  v += dpp1<0xB1>(v);
  v += dpp1<0x4E>(v);
  v += dpp1<0x141>(dpp1<0x1B>(v));   // ^4
  v += dpp1<0x128>(v);               // ^8 (row_ror:8)
#if HAS_PL16
  { auto rr = __builtin_amdgcn_permlane16_swap(__float_as_uint(v),
                                               __float_as_uint(v), false, false);
    v = __uint_as_float(rr[0]) + __uint_as_float(rr[1]); }
#else
  v += __int_as_float(__builtin_amdgcn_ds_swizzle(__float_as_int(v), 0x401F));
#endif
  auto p = __builtin_amdgcn_permlane32_swap(__float_as_uint(v),
                                            __float_as_uint(v), false, false);
  return __uint_as_float(p[0]) + __uint_as_float(p[1]);
}

// ---- REAL Givens rotations ----
template<int MT>   // reg bits 9:6 (e bits 3..0)
__device__ __forceinline__ void ry_reg(f32x2 (&s)[16], float2 cs) {
  const float c = cs.x, sn = cs.y;
  #pragma unroll
  for (int e0 = 0; e0 < 16; ++e0) {
    if (e0 & MT) continue;
    const int e1 = e0 | MT;
    f32x2 x0 = s[e0], x1 = s[e1];
    s[e0] = c * x0 - sn * x1;
    s[e1] = sn * x0 + c * x1;
  }
}
template<int P>    // lane bits 3..0 via DPP
__device__ __forceinline__ void ry_dpp(f32x2 (&s)[16], float2 cs, int lane) {
  const float c = cs.x;
  const float ss = ((lane >> P) & 1) ? cs.y : -cs.y;
  #pragma unroll
  for (int e = 0; e < 16; ++e) {
    f32x2 o;
    o.x = shufl<P>(s[e].x);
    o.y = shufl<P>(s[e].y);
    s[e] = c * s[e] + ss * o;
  }
}
__device__ __forceinline__ void ry16(f32x2 (&s)[16], float2 cs, int lane) {
  const bool H = (lane & 16) != 0;
  const float c = cs.x;
  const float ss = H ? cs.y : -cs.y;
  #pragma unroll
  for (int e = 0; e < 16; ++e) {
    f32x2 o;
    o.x = x16(s[e].x, H);
    o.y = x16(s[e].y, H);
    s[e] = c * s[e] + ss * o;
  }
}
__device__ __forceinline__ void ry5(f32x2 (&s)[16], float2 cs, int lane) {
  const int L = lane >> 5;
  const float c = cs.x;
  const float ss = L ? cs.y : -cs.y;
  #pragma unroll
  for (int e = 0; e < 16; ++e) {
    unsigned xr = __float_as_uint(s[e].x), xi = __float_as_uint(s[e].y);
    auto rr = __builtin_amdgcn_permlane32_swap(xr, xr, false, false);
    auto ri = __builtin_amdgcn_permlane32_swap(xi, xi, false, false);
    f32x2 o;
    o.x = __uint_as_float(L ? rr[0] : rr[1]);
    o.y = __uint_as_float(L ? ri[0] : ri[1]);
    s[e] = c * s[e] + ss * o;
  }
}

// CNOT permutation via private per-wave LDS slice (same-wave DS in-order,
// no barrier).
template<int R>
__device__ __forceinline__ void perm_state(f32x2 (&s)[16], f32x2* __restrict__ L,
                                           int lane) {
  constexpr int K0=cperm_c(1,R),  K1=cperm_c(2,R),  K2=cperm_c(4,R),
                K3=cperm_c(8,R),  K4=cperm_c(16,R), K5=cperm_c(32,R),
                C6=cperm_c(64,R), C7=cperm_c(128,R),
                C8=cperm_c(256,R),C9=cperm_c(512,R);
  const int yl = ((lane & 1)  ? K0 : 0) ^ ((lane & 2)  ? K1 : 0) ^
                 ((lane & 4)  ? K2 : 0) ^ ((lane & 8)  ? K3 : 0) ^
                 ((lane & 16) ? K4 : 0) ^ ((lane & 32) ? K5 : 0);
  #pragma unroll
  for (int e = 0; e < 16; ++e) {
    const int ye = ((e & 1) ? C6 : 0) ^ ((e & 2) ? C7 : 0) ^
                   ((e & 4) ? C8 : 0) ^ ((e & 8) ? C9 : 0);
    L[yl ^ ye] = s[e];
  }
  #pragma unroll
  for (int e = 0; e < 16; ++e) s[e] = L[(e << 6) | lane];
}

template<int LYR>
__device__ __forceinline__ void do_layer(f32x2 (&s)[16],
                                         const float2* __restrict__ ryc,
                                         const f32x2* __restrict__ Etab,
                                         f32x2* __restrict__ L, int lane) {
  // R12: issue the E-table loads FIRST — ~2500 cycles of gate VALU below
  // hides the L2 latency (loads were previously consumed right where they
  // issued, exposing ~1K cycles/row with only 4 waves/SIMD to cover).
  f32x2 et[16];
  if constexpr (LYR < 3) {
    const f32x2* El = Etab + LYR * 1024;
    #pragma unroll
    for (int e = 0; e < 16; ++e) et[e] = El[(e << 6) | lane];
  }
  const float2* G = ryc + LYR * 10;
  ry_reg<8>(s, G[0]);          // q0 -> bit9
  ry_reg<4>(s, G[1]);          // q1 -> bit8
  ry_reg<2>(s, G[2]);          // q2 -> bit7
  ry_reg<1>(s, G[3]);          // q3 -> bit6
  ry5     (s, G[4], lane);     // q4 -> bit5 (permlane32_swap)
  ry16    (s, G[5], lane);     // q5 -> bit4 (permlane16_swap / swizzle)
  ry_dpp<3>(s, G[6], lane);    // q6 -> bit3 (row_ror:8)
  ry_dpp<2>(s, G[7], lane);    // q7 -> bit2 (DPP)
  ry_dpp<1>(s, G[8], lane);    // q8 -> bit1 (DPP)
  ry_dpp<0>(s, G[9], lane);    // q9 -> bit0 (DPP)
  if constexpr (LYR < 3) {
    #pragma unroll
    for (int e = 0; e < 16; ++e) {       // merged omega(l)+phi(l+1) diagonal
      f32x2 t = et[e];
      f32x2 r;
      r.x = s[e].x * t.x - s[e].y * t.y;
      r.y = s[e].x * t.y + s[e].y * t.x;
      s[e] = r;
    }
    perm_state<LYR + 1>(s, L, lane);
  }
  // layer 3: omega-diag dropped (pure phase); perm folded into epilogue signs
}

// In-register Walsh-Hadamard stage over the 4 e-bits.
template<int M>
__device__ __forceinline__ void wht(float (&h)[16]) {
  #pragma unroll
  for (int e0 = 0; e0 < 16; ++e0) {
    if (e0 & M) continue;
    float u = h[e0], v = h[e0 | M];
    h[e0] = u + v;
    h[e0 | M] = u - v;
  }
}
template<int Q>
__device__ __forceinline__ float zfin(const float (&h)[16], int lane, float rn2) {
  constexpr int aq = amask(Q);
  constexpr int mq = mmask(Q);
  float t = h[mq];
  if constexpr (aq != 0) {
    int par = __builtin_popcount(lane & aq) & 1;
    t = par ? -t : t;
  }
  return red64(t) * rn2;
}

// ------------------------------------------------------- fused simulation ---
// R9/R11 structure (proven): one row per wave, 16 amps/lane, unrolled layers,
// 4 waves/SIMD, zero __syncthreads. R12: E-prefetch + 1-DPP xor8.
__global__ __launch_bounds__(256, 2) void vqc_sim(const float* __restrict__ X,
                                                  const float* __restrict__ Gg,
                                                  const float* __restrict__ W,
                                                  const float* __restrict__ bias,
                                                  float* __restrict__ out) {
  __shared__ f32x2 lds[4][DIMQ];     // 32 KB perm slices (per-wave private)
  const int lane = threadIdx.x & 63;
  const int w = threadIdx.x >> 6;
  const int row = blockIdx.x * 4 + w;
  f32x2* L = lds[w];
  const float2* ryc = (const float2*)Gg;
  const f32x2* D0   = (const f32x2*)(Gg + 128);
  const f32x2* Etab = D0 + 1024;

  f32x2 s[16];

  // ---- load; init state = x * D_phi^0 (first diagonal on real input) ----
  const float* xr = X + (size_t)row * DIMQ;
  float ss = 0.f;
  #pragma unroll
  for (int e = 0; e < 16; ++e) {
    float v = xr[(e << 6) | lane];
    ss += v * v;
    s[e] = v * D0[(e << 6) | lane];
  }
  const float rn2 = 1.0f / red64(ss);   // uniform probability scale

  do_layer<0>(s, ryc, Etab, L, lane);
  do_layer<1>(s, ryc, Etab, L, lane);
  do_layer<2>(s, ryc, Etab, L, lane);
  do_layer<3>(s, ryc, Etab, L, lane);

  // ---- probs -> z via WHT (layer-3 perm r=4 folded into signs) ----
  float h[16];
  #pragma unroll
  for (int e = 0; e < 16; ++e) h[e] = s[e].x * s[e].x + s[e].y * s[e].y;
  wht<1>(h); wht<2>(h); wht<4>(h); wht<8>(h);

  float z[10];
  z[0] = zfin<0>(h, lane, rn2);
  z[1] = zfin<1>(h, lane, rn2);
  z[2] = zfin<2>(h, lane, rn2);
  z[3] = zfin<3>(h, lane, rn2);
  z[4] = zfin<4>(h, lane, rn2);
  z[5] = zfin<5>(h, lane, rn2);
  z[6] = zfin<6>(h, lane, rn2);
  z[7] = zfin<7>(h, lane, rn2);
  z[8] = zfin<8>(h, lane, rn2);
  z[9] = zfin<9>(h, lane, rn2);

  // ---- linear head ----
  if (lane < 16) {
    float acc = bias[lane];
    #pragma unroll
    for (int q = 0; q < 10; ++q) acc += z[q] * W[lane * 10 + q];
    out[(size_t)row * 16 + lane] = acc;
  }
}

extern "C" void kernel_launch(void* const* d_in, const int* in_sizes, int n_in,
                              void* d_out, int out_size, void* d_ws, size_t ws_size,
                              hipStream_t stream) {
  const float* X    = (const float*)d_in[0];
  const float* wts  = (const float*)d_in[1];
  const float* W    = (const float*)d_in[2];
  const float* bias = (const float*)d_in[3];
  float* out = (float*)d_out;
  float* Gg = (float*)d_ws;   // 80 ry floats + pad + D0/E tables = 33 KB

  hipLaunchKernelGGL(prep_g,  dim3(1),         dim3(64),  0, stream, wts, Gg);
  hipLaunchKernelGGL(vqc_sim, dim3(BATCH / 4), dim3(256), 0, stream, X, Gg, W, bias, out);
}

// Round 13
// 99.422 us; speedup vs baseline: 1.1932x; 1.1932x over previous
//
#include <hip/hip_runtime.h>
#include <stdint.h>

#define NQ 10
#define DIMQ 1024
#define BATCH 4096

typedef float f32x2 __attribute__((ext_vector_type(2)));

#if __has_builtin(__builtin_amdgcn_permlane16_swap)
#define HAS_PL16 1
#else
#define HAS_PL16 0
#endif

// Layer's 10 CNOTs composed as a GF(2)-linear index map (scatter form).
__host__ __device__ constexpr int cperm_c(int x, int r) {
  for (int q = 0; q < NQ; ++q) {
    const int c = 9 - q;
    int t = c - r; if (t < 0) t += NQ;
    x ^= ((x >> c) & 1) << t;
  }
  return x;
}
// Epilogue sign masks (layer-3 perm r=4 folded into signs).
constexpr int amask(int q) {
  int a = 0;
  for (int b = 0; b < 6; ++b) a |= ((cperm_c(1 << b, 4) >> (9 - q)) & 1) << b;
  return a;
}
constexpr int mmask(int q) {
  int m = 0;
  for (int b = 0; b < 4; ++b) m |= ((cperm_c(1 << (6 + b), 4) >> (9 - q)) & 1) << b;
  return m;
}

// ------------------------------------------------------- gate precompute ---
// R13: prep parallelized over the 1024 table indices (R12 post-mortem: the
// 64-thread serial version cost ~35 us — as much as the main kernel).
// One thread per idx: D0[idx] and E_l[idx]; first 40 threads also emit ryc.
__global__ __launch_bounds__(256) void prep_g(const float* __restrict__ wts,
                                              float* __restrict__ Gg) {
  const int idx = blockIdx.x * 256 + threadIdx.x;   // grid 4 x 256 = 1024
  if (idx < 40) {
    float th = wts[idx * 3 + 1];
    ((float2*)Gg)[idx] = make_float2(cosf(0.5f * th), sinf(0.5f * th));
  }
  f32x2* D0 = (f32x2*)(Gg + 128);
  f32x2* E  = D0 + 1024;           // E0, E1, E2 consecutive (1024 each)
  auto sphase = [&](int l, int i, int comp) {   // comp: 0=phi, 2=omega
    float s = 0.f;
    #pragma unroll
    for (int q = 0; q < 10; ++q) {              // wts loads are uniform -> SGPR
      float sg = ((i >> (9 - q)) & 1) ? 0.5f : -0.5f;
      s += sg * wts[(l * 10 + q) * 3 + comp];
    }
    return s;
  };
  float p0 = sphase(0, idx, 0);
  D0[idx] = (f32x2){cosf(p0), sinf(p0)};
  #pragma unroll
  for (int l = 0; l < 3; ++l) {
    float a = sphase(l, idx, 2) + sphase(l + 1, cperm_c(idx, l + 1), 0);
    E[l * 1024 + idx] = (f32x2){cosf(a), sinf(a)};
  }
}

// ---- VALU-pipe lane shuffles ----
template<int CTRL>
__device__ __forceinline__ float dpp1(float x) {
  return __int_as_float(
      __builtin_amdgcn_update_dpp(0, __float_as_int(x), CTRL, 0xF, 0xF, true));
}
// quad_perm xor1=0xB1, xor2=0x4E, xor3=0x1B; row_half_mirror(^7)=0x141;
// row_ror:8 = 0x128 == xor8 within a 16-lane row.
template<int P>   // P = lane bit, 0..3 (DPP only)
__device__ __forceinline__ float shufl(float x) {
  if constexpr (P == 0)      return dpp1<0xB1>(x);
  else if constexpr (P == 1) return dpp1<0x4E>(x);
  else if constexpr (P == 2) return dpp1<0x141>(dpp1<0x1B>(x));
  else                       return dpp1<0x128>(x);   // row_ror:8 == ^8
}
__device__ __forceinline__ float x16(float x, bool hi) {
#if HAS_PL16
  auto rr = __builtin_amdgcn_permlane16_swap(__float_as_uint(x),
                                             __float_as_uint(x), false, false);
  return __uint_as_float(hi ? rr[0] : rr[1]);
#else
  (void)hi;
  return __int_as_float(__builtin_amdgcn_ds_swizzle(__float_as_int(x), 0x401F));
#endif
}

// Wave sum -> uniform scalar.
__device__ __forceinline__ float red64(float v) {
  v += dpp1<0xB1>(v);
  v += dpp1<0x4E>(v);
  v += dpp1<0x141>(dpp1<0x1B>(v));   // ^4
  v += dpp1<0x128>(v);               // ^8 (row_ror:8)
#if HAS_PL16
  { auto rr = __builtin_amdgcn_permlane16_swap(__float_as_uint(v),
                                               __float_as_uint(v), false, false);
    v = __uint_as_float(rr[0]) + __uint_as_float(rr[1]); }
#else
  v += __int_as_float(__builtin_amdgcn_ds_swizzle(__float_as_int(v), 0x401F));
#endif
  auto p = __builtin_amdgcn_permlane32_swap(__float_as_uint(v),
                                            __float_as_uint(v), false, false);
  return __uint_as_float(p[0]) + __uint_as_float(p[1]);
}

// ---- REAL Givens rotations ----
template<int MT>   // reg bits 9:6 (e bits 3..0)
__device__ __forceinline__ void ry_reg(f32x2 (&s)[16], float2 cs) {
  const float c = cs.x, sn = cs.y;
  #pragma unroll
  for (int e0 = 0; e0 < 16; ++e0) {
    if (e0 & MT) continue;
    const int e1 = e0 | MT;
    f32x2 x0 = s[e0], x1 = s[e1];
    s[e0] = c * x0 - sn * x1;
    s[e1] = sn * x0 + c * x1;
  }
}
template<int P>    // lane bits 3..0 via DPP
__device__ __forceinline__ void ry_dpp(f32x2 (&s)[16], float2 cs, int lane) {
  const float c = cs.x;
  const float ss = ((lane >> P) & 1) ? cs.y : -cs.y;
  #pragma unroll
  for (int e = 0; e < 16; ++e) {
    f32x2 o;
    o.x = shufl<P>(s[e].x);
    o.y = shufl<P>(s[e].y);
    s[e] = c * s[e] + ss * o;
  }
}
__device__ __forceinline__ void ry16(f32x2 (&s)[16], float2 cs, int lane) {
  const bool H = (lane & 16) != 0;
  const float c = cs.x;
  const float ss = H ? cs.y : -cs.y;
  #pragma unroll
  for (int e = 0; e < 16; ++e) {
    f32x2 o;
    o.x = x16(s[e].x, H);
    o.y = x16(s[e].y, H);
    s[e] = c * s[e] + ss * o;
  }
}
__device__ __forceinline__ void ry5(f32x2 (&s)[16], float2 cs, int lane) {
  const int L = lane >> 5;
  const float c = cs.x;
  const float ss = L ? cs.y : -cs.y;
  #pragma unroll
  for (int e = 0; e < 16; ++e) {
    unsigned xr = __float_as_uint(s[e].x), xi = __float_as_uint(s[e].y);
    auto rr = __builtin_amdgcn_permlane32_swap(xr, xr, false, false);
    auto ri = __builtin_amdgcn_permlane32_swap(xi, xi, false, false);
    f32x2 o;
    o.x = __uint_as_float(L ? rr[0] : rr[1]);
    o.y = __uint_as_float(L ? ri[0] : ri[1]);
    s[e] = c * s[e] + ss * o;
  }
}

// CNOT permutation via private per-wave LDS slice (same-wave DS in-order,
// no barrier).
template<int R>
__device__ __forceinline__ void perm_state(f32x2 (&s)[16], f32x2* __restrict__ L,
                                           int lane) {
  constexpr int K0=cperm_c(1,R),  K1=cperm_c(2,R),  K2=cperm_c(4,R),
                K3=cperm_c(8,R),  K4=cperm_c(16,R), K5=cperm_c(32,R),
                C6=cperm_c(64,R), C7=cperm_c(128,R),
                C8=cperm_c(256,R),C9=cperm_c(512,R);
  const int yl = ((lane & 1)  ? K0 : 0) ^ ((lane & 2)  ? K1 : 0) ^
                 ((lane & 4)  ? K2 : 0) ^ ((lane & 8)  ? K3 : 0) ^
                 ((lane & 16) ? K4 : 0) ^ ((lane & 32) ? K5 : 0);
  #pragma unroll
  for (int e = 0; e < 16; ++e) {
    const int ye = ((e & 1) ? C6 : 0) ^ ((e & 2) ? C7 : 0) ^
                   ((e & 4) ? C8 : 0) ^ ((e & 8) ? C9 : 0);
    L[yl ^ ye] = s[e];
  }
  #pragma unroll
  for (int e = 0; e < 16; ++e) s[e] = L[(e << 6) | lane];
}

template<int LYR>
__device__ __forceinline__ void do_layer(f32x2 (&s)[16],
                                         const float2* __restrict__ ryc,
                                         const f32x2* __restrict__ Etab,
                                         f32x2* __restrict__ L, int lane) {
  // E-table loads issued FIRST; ~2500 cycles of gate VALU below hides L2.
  f32x2 et[16];
  if constexpr (LYR < 3) {
    const f32x2* El = Etab + LYR * 1024;
    #pragma unroll
    for (int e = 0; e < 16; ++e) et[e] = El[(e << 6) | lane];
  }
  const float2* G = ryc + LYR * 10;
  ry_reg<8>(s, G[0]);          // q0 -> bit9
  ry_reg<4>(s, G[1]);          // q1 -> bit8
  ry_reg<2>(s, G[2]);          // q2 -> bit7
  ry_reg<1>(s, G[3]);          // q3 -> bit6
  ry5     (s, G[4], lane);     // q4 -> bit5 (permlane32_swap)
  ry16    (s, G[5], lane);     // q5 -> bit4 (permlane16_swap / swizzle)
  ry_dpp<3>(s, G[6], lane);    // q6 -> bit3 (row_ror:8)
  ry_dpp<2>(s, G[7], lane);    // q7 -> bit2 (DPP)
  ry_dpp<1>(s, G[8], lane);    // q8 -> bit1 (DPP)
  ry_dpp<0>(s, G[9], lane);    // q9 -> bit0 (DPP)
  if constexpr (LYR < 3) {
    #pragma unroll
    for (int e = 0; e < 16; ++e) {       // merged omega(l)+phi(l+1) diagonal
      f32x2 t = et[e];
      f32x2 r;
      r.x = s[e].x * t.x - s[e].y * t.y;
      r.y = s[e].x * t.y + s[e].y * t.x;
      s[e] = r;
    }
    perm_state<LYR + 1>(s, L, lane);
  }
  // layer 3: omega-diag dropped (pure phase); perm folded into epilogue signs
}

// In-register Walsh-Hadamard stage over the 4 e-bits.
template<int M>
__device__ __forceinline__ void wht(float (&h)[16]) {
  #pragma unroll
  for (int e0 = 0; e0 < 16; ++e0) {
    if (e0 & M) continue;
    float u = h[e0], v = h[e0 | M];
    h[e0] = u + v;
    h[e0 | M] = u - v;
  }
}
template<int Q>
__device__ __forceinline__ float zfin(const float (&h)[16], int lane, float rn2) {
  constexpr int aq = amask(Q);
  constexpr int mq = mmask(Q);
  float t = h[mq];
  if constexpr (aq != 0) {
    int par = __builtin_popcount(lane & aq) & 1;
    t = par ? -t : t;
  }
  return red64(t) * rn2;
}

// ------------------------------------------------------- fused simulation ---
// R12 structure unchanged (<=42 us): one row per wave, 16 amps/lane, unrolled
// layers, 4 waves/SIMD, zero __syncthreads, E-prefetch.
__global__ __launch_bounds__(256, 2) void vqc_sim(const float* __restrict__ X,
                                                  const float* __restrict__ Gg,
                                                  const float* __restrict__ W,
                                                  const float* __restrict__ bias,
                                                  float* __restrict__ out) {
  __shared__ f32x2 lds[4][DIMQ];     // 32 KB perm slices (per-wave private)
  const int lane = threadIdx.x & 63;
  const int w = threadIdx.x >> 6;
  const int row = blockIdx.x * 4 + w;
  f32x2* L = lds[w];
  const float2* ryc = (const float2*)Gg;
  const f32x2* D0   = (const f32x2*)(Gg + 128);
  const f32x2* Etab = D0 + 1024;

  f32x2 s[16];

  // ---- load; init state = x * D_phi^0 (first diagonal on real input) ----
  const float* xr = X + (size_t)row * DIMQ;
  float ss = 0.f;
  #pragma unroll
  for (int e = 0; e < 16; ++e) {
    float v = xr[(e << 6) | lane];
    ss += v * v;
    s[e] = v * D0[(e << 6) | lane];
  }
  const float rn2 = 1.0f / red64(ss);   // uniform probability scale

  do_layer<0>(s, ryc, Etab, L, lane);
  do_layer<1>(s, ryc, Etab, L, lane);
  do_layer<2>(s, ryc, Etab, L, lane);
  do_layer<3>(s, ryc, Etab, L, lane);

  // ---- probs -> z via WHT (layer-3 perm r=4 folded into signs) ----
  float h[16];
  #pragma unroll
  for (int e = 0; e < 16; ++e) h[e] = s[e].x * s[e].x + s[e].y * s[e].y;
  wht<1>(h); wht<2>(h); wht<4>(h); wht<8>(h);

  float z[10];
  z[0] = zfin<0>(h, lane, rn2);
  z[1] = zfin<1>(h, lane, rn2);
  z[2] = zfin<2>(h, lane, rn2);
  z[3] = zfin<3>(h, lane, rn2);
  z[4] = zfin<4>(h, lane, rn2);
  z[5] = zfin<5>(h, lane, rn2);
  z[6] = zfin<6>(h, lane, rn2);
  z[7] = zfin<7>(h, lane, rn2);
  z[8] = zfin<8>(h, lane, rn2);
  z[9] = zfin<9>(h, lane, rn2);

  // ---- linear head ----
  if (lane < 16) {
    float acc = bias[lane];
    #pragma unroll
    for (int q = 0; q < 10; ++q) acc += z[q] * W[lane * 10 + q];
    out[(size_t)row * 16 + lane] = acc;
  }
}

extern "C" void kernel_launch(void* const* d_in, const int* in_sizes, int n_in,
                              void* d_out, int out_size, void* d_ws, size_t ws_size,
                              hipStream_t stream) {
  const float* X    = (const float*)d_in[0];
  const float* wts  = (const float*)d_in[1];
  const float* W    = (const float*)d_in[2];
  const float* bias = (const float*)d_in[3];
  float* out = (float*)d_out;
  float* Gg = (float*)d_ws;   // 80 ry floats + pad + D0/E tables = 33 KB

  hipLaunchKernelGGL(prep_g,  dim3(4),         dim3(256), 0, stream, wts, Gg);
  hipLaunchKernelGGL(vqc_sim, dim3(BATCH / 4), dim3(256), 0, stream, X, Gg, W, bias, out);
}